// Round 1
// baseline (892.057 us; speedup 1.0000x reference)
//
#include <hip/hip_runtime.h>
#include <hip/hip_bf16.h>

// ---------------- CSR build ----------------

__global__ void k_count(const int* __restrict__ dst, int* __restrict__ cnt, int E) {
  int e = blockIdx.x * 256 + threadIdx.x;
  if (e < E) atomicAdd(&cnt[dst[e]], 1);
}

__global__ void k_scan1(const int* __restrict__ cnt, int* __restrict__ bsum, int N) {
  __shared__ int sh[256];
  int t = threadIdx.x;
  int base = blockIdx.x * 1024 + t * 4;
  int s = 0;
  #pragma unroll
  for (int q = 0; q < 4; ++q) { int i = base + q; if (i < N) s += cnt[i]; }
  sh[t] = s; __syncthreads();
  for (int off = 128; off > 0; off >>= 1) {
    if (t < off) sh[t] += sh[t + off];
    __syncthreads();
  }
  if (t == 0) bsum[blockIdx.x] = sh[0];
}

__global__ void k_scan2(const int* __restrict__ bsum, int* __restrict__ boff,
                        int* __restrict__ row_ptr, int NB, int N) {
  __shared__ int sh[128];
  int t = threadIdx.x;
  int v = (t < NB) ? bsum[t] : 0;
  sh[t] = v; __syncthreads();
  for (int off = 1; off < 128; off <<= 1) {
    int y = (t >= off) ? sh[t - off] : 0;
    __syncthreads();
    sh[t] += y;
    __syncthreads();
  }
  if (t < NB) boff[t] = sh[t] - v;
  if (t == 127) row_ptr[N] = sh[127];
}

__global__ void k_scan3(const int* __restrict__ cnt, const int* __restrict__ boff,
                        int* __restrict__ row_ptr, int N) {
  __shared__ int sh[256];
  int t = threadIdx.x;
  int base = blockIdx.x * 1024 + t * 4;
  int c0 = 0, c1 = 0, c2 = 0, c3 = 0;
  if (base + 0 < N) c0 = cnt[base + 0];
  if (base + 1 < N) c1 = cnt[base + 1];
  if (base + 2 < N) c2 = cnt[base + 2];
  if (base + 3 < N) c3 = cnt[base + 3];
  int s = c0 + c1 + c2 + c3;
  sh[t] = s; __syncthreads();
  for (int off = 1; off < 256; off <<= 1) {
    int y = (t >= off) ? sh[t - off] : 0;
    __syncthreads();
    sh[t] += y;
    __syncthreads();
  }
  int run = boff[blockIdx.x] + sh[t] - s;
  if (base + 0 < N) row_ptr[base + 0] = run; run += c0;
  if (base + 1 < N) row_ptr[base + 1] = run; run += c1;
  if (base + 2 < N) row_ptr[base + 2] = run; run += c2;
  if (base + 3 < N) row_ptr[base + 3] = run;
}

__global__ void k_fill(const int* __restrict__ src, const int* __restrict__ dst,
                       int* __restrict__ cursor, int* __restrict__ csr_src, int E) {
  int e = blockIdx.x * 256 + threadIdx.x;
  if (e < E) {
    int pos = atomicAdd(&cursor[dst[e]], 1);
    csr_src[pos] = src[e];
  }
}

// ---------------- SAGE layer: fused gather-mean + transform + ReLU ----------------
// One thread per node. feat row + neighbor mean in registers (static indexing only);
// W^T staged in LDS, read as wave-uniform broadcast float4 (conflict-free).

__global__ __launch_bounds__(256) void k_sage(
    const float* __restrict__ feat, const int* __restrict__ rp, const int* __restrict__ csrc,
    const float* __restrict__ Ws, const float* __restrict__ Wn, const float* __restrict__ bias,
    float* __restrict__ out, int N)
{
  __shared__ float sWsT[64 * 64];
  __shared__ float sWnT[64 * 64];
  __shared__ float sb[64];
  for (int idx = threadIdx.x; idx < 4096; idx += 256) {
    int k = idx >> 6, j = idx & 63;
    sWsT[j * 64 + k] = Ws[idx];
    sWnT[j * 64 + k] = Wn[idx];
  }
  if (threadIdx.x < 64) sb[threadIdx.x] = bias[threadIdx.x];
  __syncthreads();

  int i = blockIdx.x * 256 + threadIdx.x;
  if (i >= N) return;

  const float4* feat4 = (const float4*)feat;
  float f[64];
  #pragma unroll
  for (int q = 0; q < 16; ++q) {
    float4 v = feat4[(size_t)i * 16 + q];
    f[4*q+0] = v.x; f[4*q+1] = v.y; f[4*q+2] = v.z; f[4*q+3] = v.w;
  }
  float nv[64];
  #pragma unroll
  for (int q = 0; q < 64; ++q) nv[q] = 0.f;

  int e0 = rp[i], e1 = rp[i + 1];
  for (int e = e0; e < e1; ++e) {
    int s = csrc[e];
    #pragma unroll
    for (int q = 0; q < 16; ++q) {
      float4 v = feat4[(size_t)s * 16 + q];
      nv[4*q+0] += v.x; nv[4*q+1] += v.y; nv[4*q+2] += v.z; nv[4*q+3] += v.w;
    }
  }
  int len = e1 - e0;
  float inv = 1.f / (float)(len > 0 ? len : 1);
  #pragma unroll
  for (int q = 0; q < 64; ++q) nv[q] *= inv;

  const float4* A4 = (const float4*)sWsT;
  const float4* B4 = (const float4*)sWnT;
  float* orow = out + (size_t)i * 64;
  #pragma unroll 1
  for (int j = 0; j < 64; ++j) {
    float acc = sb[j];
    #pragma unroll
    for (int q = 0; q < 16; ++q) {
      float4 w = A4[j * 16 + q];
      acc += f[4*q+0]*w.x + f[4*q+1]*w.y + f[4*q+2]*w.z + f[4*q+3]*w.w;
      float4 u = B4[j * 16 + q];
      acc += nv[4*q+0]*u.x + nv[4*q+1]*u.y + nv[4*q+2]*u.z + nv[4*q+3]*u.w;
    }
    orow[j] = fmaxf(acc, 0.f);
  }
}

// ---------------- head precompute: za = h@W1[0:64], zb = h@W1[64:128] ----------------

__global__ __launch_bounds__(256) void k_zab(
    const float* __restrict__ hf, const float* __restrict__ W1,
    float* __restrict__ za, float* __restrict__ zb, int N)
{
  __shared__ float sAT[64 * 64];
  __shared__ float sBT[64 * 64];
  for (int idx = threadIdx.x; idx < 4096; idx += 256) {
    int k = idx >> 6, j = idx & 63;
    sAT[j * 64 + k] = W1[idx];
    sBT[j * 64 + k] = W1[4096 + idx];
  }
  __syncthreads();
  int i = blockIdx.x * 256 + threadIdx.x;
  if (i >= N) return;
  const float4* h4 = (const float4*)hf;
  float f[64];
  #pragma unroll
  for (int q = 0; q < 16; ++q) {
    float4 v = h4[(size_t)i * 16 + q];
    f[4*q+0] = v.x; f[4*q+1] = v.y; f[4*q+2] = v.z; f[4*q+3] = v.w;
  }
  const float4* A4 = (const float4*)sAT;
  const float4* B4 = (const float4*)sBT;
  float* zar = za + (size_t)i * 64;
  float* zbr = zb + (size_t)i * 64;
  #pragma unroll 1
  for (int j = 0; j < 64; ++j) {
    float aa = 0.f, bb = 0.f;
    #pragma unroll
    for (int q = 0; q < 16; ++q) {
      float4 w = A4[j * 16 + q];
      aa += f[4*q+0]*w.x + f[4*q+1]*w.y + f[4*q+2]*w.z + f[4*q+3]*w.w;
      float4 u = B4[j * 16 + q];
      bb += f[4*q+0]*u.x + f[4*q+1]*u.y + f[4*q+2]*u.z + f[4*q+3]*u.w;
    }
    zar[j] = aa; zbr[j] = bb;
  }
}

// ---------------- head: out = relu(za[x1]+zb[x2]+|h1-h2|@W1c + b1) @ W2 + b2 ----------------
// One thread per pair; j-loop fully unrolled so a[]/zs[] stay in registers.

__global__ __launch_bounds__(256) void k_head_z(
    const float* __restrict__ hf, const float* __restrict__ za, const float* __restrict__ zb,
    const int* __restrict__ x1, const int* __restrict__ x2,
    const float* __restrict__ W1, const float* __restrict__ bl1,
    const float* __restrict__ W2, const float* __restrict__ bl2,
    float* __restrict__ out, int P)
{
  __shared__ float sCT[64 * 64];
  __shared__ float sW2[128];
  __shared__ float sb1[64];
  __shared__ float sb2[2];
  for (int idx = threadIdx.x; idx < 4096; idx += 256) {
    int k = idx >> 6, j = idx & 63;
    sCT[j * 64 + k] = W1[8192 + idx];   // W1 rows 128..191, transposed
  }
  if (threadIdx.x < 128) sW2[threadIdx.x] = W2[threadIdx.x];
  if (threadIdx.x < 64)  sb1[threadIdx.x] = bl1[threadIdx.x];
  if (threadIdx.x < 2)   sb2[threadIdx.x] = bl2[threadIdx.x];
  __syncthreads();

  int p = blockIdx.x * 256 + threadIdx.x;
  if (p >= P) return;
  int i1 = x1[p], i2 = x2[p];
  const float4* h4 = (const float4*)hf;
  const float4* za4 = (const float4*)za;
  const float4* zb4 = (const float4*)zb;
  float a[64], zs[64];
  #pragma unroll
  for (int q = 0; q < 16; ++q) {
    float4 v1 = h4[(size_t)i1 * 16 + q];
    float4 v2 = h4[(size_t)i2 * 16 + q];
    a[4*q+0] = fabsf(v1.x - v2.x);
    a[4*q+1] = fabsf(v1.y - v2.y);
    a[4*q+2] = fabsf(v1.z - v2.z);
    a[4*q+3] = fabsf(v1.w - v2.w);
    float4 u1 = za4[(size_t)i1 * 16 + q];
    float4 u2 = zb4[(size_t)i2 * 16 + q];
    zs[4*q+0] = u1.x + u2.x;
    zs[4*q+1] = u1.y + u2.y;
    zs[4*q+2] = u1.z + u2.z;
    zs[4*q+3] = u1.w + u2.w;
  }
  const float4* C4 = (const float4*)sCT;
  float o0 = 0.f, o1 = 0.f;
  #pragma unroll
  for (int j = 0; j < 64; ++j) {
    float acc = sb1[j] + zs[j];
    #pragma unroll
    for (int q = 0; q < 16; ++q) {
      float4 w = C4[j * 16 + q];
      acc += a[4*q+0]*w.x + a[4*q+1]*w.y + a[4*q+2]*w.z + a[4*q+3]*w.w;
    }
    float r = fmaxf(acc, 0.f);
    o0 += r * sW2[2*j + 0];
    o1 += r * sW2[2*j + 1];
  }
  out[(size_t)p * 2 + 0] = o0 + sb2[0];
  out[(size_t)p * 2 + 1] = o1 + sb2[1];
}

// ---------------- fallback head (if ws too small for za/zb): direct 192-wide GEMV ----------------

__global__ __launch_bounds__(256) void k_head_direct(
    const float* __restrict__ hf, const int* __restrict__ x1, const int* __restrict__ x2,
    const float* __restrict__ W1, const float* __restrict__ bl1,
    const float* __restrict__ W2, const float* __restrict__ bl2,
    float* __restrict__ out, int P)
{
  __shared__ float sW1T[64 * 192];
  __shared__ float sW2[128];
  __shared__ float sb1[64];
  __shared__ float sb2[2];
  for (int idx = threadIdx.x; idx < 12288; idx += 256) {
    int k = idx >> 6, j = idx & 63;
    sW1T[j * 192 + k] = W1[idx];
  }
  if (threadIdx.x < 128) sW2[threadIdx.x] = W2[threadIdx.x];
  if (threadIdx.x < 64)  sb1[threadIdx.x] = bl1[threadIdx.x];
  if (threadIdx.x < 2)   sb2[threadIdx.x] = bl2[threadIdx.x];
  __syncthreads();

  int p = blockIdx.x * 256 + threadIdx.x;
  if (p >= P) return;
  int i1 = x1[p], i2 = x2[p];
  const float4* h4 = (const float4*)hf;
  float h1[64], h2[64], a[64];
  #pragma unroll
  for (int q = 0; q < 16; ++q) {
    float4 v1 = h4[(size_t)i1 * 16 + q];
    float4 v2 = h4[(size_t)i2 * 16 + q];
    h1[4*q+0] = v1.x; h1[4*q+1] = v1.y; h1[4*q+2] = v1.z; h1[4*q+3] = v1.w;
    h2[4*q+0] = v2.x; h2[4*q+1] = v2.y; h2[4*q+2] = v2.z; h2[4*q+3] = v2.w;
    a[4*q+0] = fabsf(v1.x - v2.x);
    a[4*q+1] = fabsf(v1.y - v2.y);
    a[4*q+2] = fabsf(v1.z - v2.z);
    a[4*q+3] = fabsf(v1.w - v2.w);
  }
  float o0 = 0.f, o1 = 0.f;
  #pragma unroll 1
  for (int j = 0; j < 64; ++j) {
    float acc = sb1[j];
    const float4* row = (const float4*)&sW1T[j * 192];
    #pragma unroll
    for (int q = 0; q < 16; ++q) {
      float4 w = row[q];
      acc += h1[4*q+0]*w.x + h1[4*q+1]*w.y + h1[4*q+2]*w.z + h1[4*q+3]*w.w;
    }
    #pragma unroll
    for (int q = 0; q < 16; ++q) {
      float4 w = row[16 + q];
      acc += h2[4*q+0]*w.x + h2[4*q+1]*w.y + h2[4*q+2]*w.z + h2[4*q+3]*w.w;
    }
    #pragma unroll
    for (int q = 0; q < 16; ++q) {
      float4 w = row[32 + q];
      acc += a[4*q+0]*w.x + a[4*q+1]*w.y + a[4*q+2]*w.z + a[4*q+3]*w.w;
    }
    float r = fmaxf(acc, 0.f);
    o0 += r * sW2[2*j + 0];
    o1 += r * sW2[2*j + 1];
  }
  out[(size_t)p * 2 + 0] = o0 + sb2[0];
  out[(size_t)p * 2 + 1] = o1 + sb2[1];
}

// ---------------- launch ----------------

extern "C" void kernel_launch(void* const* d_in, const int* in_sizes, int n_in,
                              void* d_out, int out_size, void* d_ws, size_t ws_size,
                              hipStream_t stream)
{
  (void)n_in; (void)out_size;
  const float* h   = (const float*)d_in[0];
  const int*   src = (const int*)d_in[1];
  const int*   dst = (const int*)d_in[2];
  const int*   x1  = (const int*)d_in[3];
  const int*   x2  = (const int*)d_in[4];
  const float* Ws0 = (const float*)d_in[5];
  const float* Wn0 = (const float*)d_in[6];
  const float* b0  = (const float*)d_in[7];
  const float* Ws1 = (const float*)d_in[8];
  const float* Wn1 = (const float*)d_in[9];
  const float* b1  = (const float*)d_in[10];
  const float* W1  = (const float*)d_in[11];
  const float* bl1 = (const float*)d_in[12];
  const float* W2  = (const float*)d_in[13];
  const float* bl2 = (const float*)d_in[14];

  const int N = in_sizes[0] / 64;
  const int E = in_sizes[1];
  const int P = in_sizes[3];
  float* out = (float*)d_out;

  char* ws = (char*)d_ws;
  size_t off = 0;
  auto carve = [&](size_t bytes) {
    char* p = ws + off;
    off = (off + bytes + 255) & ~(size_t)255;
    return p;
  };
  int*   cnt     = (int*)carve((size_t)N * 4);
  int*   row_ptr = (int*)carve((size_t)(N + 1) * 4);
  int*   cursor  = (int*)carve((size_t)N * 4);
  int*   bsum    = (int*)carve(512);
  int*   boff    = (int*)carve(512);
  int*   csr_src = (int*)carve((size_t)E * 4);
  float* buf1    = (float*)carve((size_t)N * 64 * 4);
  float* buf2    = (float*)carve((size_t)N * 64 * 4);
  float* zb      = (float*)carve((size_t)N * 64 * 4);
  size_t need_z  = off;
  bool use_z = (ws_size >= need_z);
  float* za = buf1;  // buf1 is free after layer 1 consumes it

  const int NB = (N + 1023) / 1024;

  hipMemsetAsync(cnt, 0, (size_t)N * 4, stream);
  k_count<<<(E + 255) / 256, 256, 0, stream>>>(dst, cnt, E);
  k_scan1<<<NB, 256, 0, stream>>>(cnt, bsum, N);
  k_scan2<<<1, 128, 0, stream>>>(bsum, boff, row_ptr, NB, N);
  k_scan3<<<NB, 256, 0, stream>>>(cnt, boff, row_ptr, N);
  hipMemcpyAsync(cursor, row_ptr, (size_t)N * 4, hipMemcpyDeviceToDevice, stream);
  k_fill<<<(E + 255) / 256, 256, 0, stream>>>(src, dst, cursor, csr_src, E);

  const int nbN = (N + 255) / 256;
  k_sage<<<nbN, 256, 0, stream>>>(h,    row_ptr, csr_src, Ws0, Wn0, b0, buf1, N);
  k_sage<<<nbN, 256, 0, stream>>>(buf1, row_ptr, csr_src, Ws1, Wn1, b1, buf2, N);

  const int nbP = (P + 255) / 256;
  if (use_z) {
    k_zab<<<nbN, 256, 0, stream>>>(buf2, W1, za, zb, N);
    k_head_z<<<nbP, 256, 0, stream>>>(buf2, za, zb, x1, x2, W1, bl1, W2, bl2, out, P);
  } else {
    k_head_direct<<<nbP, 256, 0, stream>>>(buf2, x1, x2, W1, bl1, W2, bl2, out, P);
  }
}